// Round 1
// baseline (389.069 us; speedup 1.0000x reference)
//
#include <hip/hip_runtime.h>

#define NB    4096      // histogram buckets over [0,1)
#define CAP   4096      // per-batch collect capacity (expected ~64 in threshold bucket)
#define BATCH 32
#define NTOK  262144    // 512*512

__device__ __forceinline__ int bucket_of(float v) {
    int b = (int)(v * (float)NB);
    return b > NB - 1 ? NB - 1 : b;
}

// --- Pass 1: per-batch histogram of s_map values ---
__global__ void hist_kernel(const float* __restrict__ smap, int* __restrict__ hist,
                            int cbpb) {
    __shared__ int lh[NB];
    for (int i = threadIdx.x; i < NB; i += blockDim.x) lh[i] = 0;
    __syncthreads();
    int b  = blockIdx.x / cbpb;
    int cb = blockIdx.x % cbpb;
    int chunk = NTOK / cbpb;
    const float4* src = (const float4*)(smap + (size_t)b * NTOK + (size_t)cb * chunk);
    int nf4 = chunk / 4;
    for (int i = threadIdx.x; i < nf4; i += blockDim.x) {
        float4 v = src[i];
        atomicAdd(&lh[bucket_of(v.x)], 1);
        atomicAdd(&lh[bucket_of(v.y)], 1);
        atomicAdd(&lh[bucket_of(v.z)], 1);
        atomicAdd(&lh[bucket_of(v.w)], 1);
    }
    __syncthreads();
    int* gh = hist + b * NB;
    for (int i = threadIdx.x; i < NB; i += blockDim.x) {
        int c = lh[i];
        if (c) atomicAdd(&gh[i], c);
    }
}

// --- Pass 2: find threshold bucket tb and residual rank R (1..hist[tb]) ---
__global__ void select_kernel(const int* __restrict__ hist, const int* __restrict__ kptr,
                              int* __restrict__ tbR) {
    int b = blockIdx.x;
    const int* gh = hist + b * NB;
    __shared__ int h[NB];
    __shared__ int csum[256];
    __shared__ int above[256];
    int t = threadIdx.x;
    const int C = NB / 256;  // 16 buckets per thread
    int base = t * C;
    int s = 0;
    for (int i = 0; i < C; i++) { int v = gh[base + i]; h[base + i] = v; s += v; }
    csum[t] = s;
    __syncthreads();
    if (t == 0) {
        int acc = 0;
        for (int c = 255; c >= 0; c--) { above[c] = acc; acc += csum[c]; }
    }
    __syncthreads();
    int K = *kptr;
    int cum = above[t];  // count of elements in buckets strictly above this chunk
    for (int i = C - 1; i >= 0; i--) {
        int hb = h[base + i];
        if (cum < K && cum + hb >= K) {
            tbR[2 * b]     = base + i;   // threshold bucket
            tbR[2 * b + 1] = K - cum;    // need R elements from it
        }
        cum += hb;
    }
}

// --- Pass 3: collect (value, index) of all elements in the threshold bucket ---
__global__ void collect_kernel(const float* __restrict__ smap, const int* __restrict__ tbR,
                               int* __restrict__ cnt, float* __restrict__ cval,
                               int* __restrict__ cidx, int cbpb) {
    int b  = blockIdx.x / cbpb;
    int cb = blockIdx.x % cbpb;
    int chunk = NTOK / cbpb;
    int tb = tbR[2 * b];
    const float4* src = (const float4*)(smap + (size_t)b * NTOK + (size_t)cb * chunk);
    int nf4 = chunk / 4;
    int base_n = cb * chunk;
    for (int i = threadIdx.x; i < nf4; i += blockDim.x) {
        float4 v = src[i];
        float vals[4] = {v.x, v.y, v.z, v.w};
#pragma unroll
        for (int s = 0; s < 4; s++) {
            if (bucket_of(vals[s]) == tb) {
                int p = atomicAdd(&cnt[b], 1);
                if (p < CAP) {
                    cval[b * CAP + p] = vals[s];
                    cidx[b * CAP + p] = base_n + 4 * i + s;
                }
            }
        }
    }
}

// --- Pass 4: exact rank-(R-1) element under (value desc, index asc) ---
__global__ void refine_kernel(const int* __restrict__ tbR, const int* __restrict__ cnt,
                              const float* __restrict__ cval, const int* __restrict__ cidx,
                              float* __restrict__ T, int* __restrict__ ncut) {
    int b = blockIdx.x;
    int R = tbR[2 * b + 1];
    int M = cnt[b];
    bool overflow = (M > CAP);
    if (M > CAP) M = CAP;
    __shared__ float sv[CAP];
    __shared__ int   si[CAP];
    for (int i = threadIdx.x; i < M; i += blockDim.x) {
        sv[i] = cval[b * CAP + i];
        si[i] = cidx[b * CAP + i];
    }
    __syncthreads();
    if (overflow || R > M || R < 1) {
        // approximate fallback (essentially never hit): take whole bucket
        if (threadIdx.x == 0) { T[b] = (float)tbR[2 * b] / (float)NB; ncut[b] = 0x7fffffff; }
        return;
    }
    for (int i = threadIdx.x; i < M; i += blockDim.x) {
        float vi = sv[i]; int ii = si[i];
        int r = 0;
        for (int j = 0; j < M; j++) {
            float vj = sv[j];
            r += (vj > vi) || (vj == vi && si[j] < ii);
        }
        if (r == R - 1) { T[b] = vi; ncut[b] = ii; }  // unique rank -> single writer
    }
}

// --- Pass 5: fused gumbel-softmax BCE loss with threshold selection ---
__global__ void loss_kernel(const float* __restrict__ ds, const float* __restrict__ u,
                            const float* __restrict__ smap, const float* __restrict__ T,
                            const int* __restrict__ ncut, float* __restrict__ out) {
    int tid = blockIdx.x * blockDim.x + threadIdx.x;  // one thread = 2 tokens
    int b = tid >> 17;              // NTOK/2 = 131072 = 2^17
    int p = tid & (131072 - 1);
    const float4* ds4 = (const float4*)(ds + (size_t)b * NTOK * 2);
    const float4* u4  = (const float4*)(u  + (size_t)b * NTOK * 2);
    const float2* s2  = (const float2*)(smap + (size_t)b * NTOK);
    float4 d4 = ds4[p];
    float4 uv = u4[p];
    float2 v2 = s2[p];
    float Tb = T[b];
    int   nc = ncut[b];
    int   n0 = p << 1;

    float acc = 0.f;
    {
        float g0 = -__logf(-__logf(uv.x));
        float g1 = -__logf(-__logf(uv.y));
        float dd = (d4.x + g0) - (d4.y + g1);
        float l  = __logf(1.f + __expf(-fabsf(dd)));
        float lp0 = (dd >= 0.f) ? -l       : dd - l;
        float lp1 = (dd >= 0.f) ? -l - dd  : -l;
        lp0 = fmaxf(lp0, -100.f); lp1 = fmaxf(lp1, -100.f);
        bool sel = (v2.x > Tb) || (v2.x == Tb && n0 <= nc);
        acc -= sel ? lp0 : lp1;
    }
    {
        float g0 = -__logf(-__logf(uv.z));
        float g1 = -__logf(-__logf(uv.w));
        float dd = (d4.z + g0) - (d4.w + g1);
        float l  = __logf(1.f + __expf(-fabsf(dd)));
        float lp0 = (dd >= 0.f) ? -l       : dd - l;
        float lp1 = (dd >= 0.f) ? -l - dd  : -l;
        lp0 = fmaxf(lp0, -100.f); lp1 = fmaxf(lp1, -100.f);
        bool sel = (v2.y > Tb) || (v2.y == Tb && (n0 + 1) <= nc);
        acc -= sel ? lp0 : lp1;
    }

    // wave(64) reduce, then cross-wave via LDS, one atomic per block
    for (int off = 32; off > 0; off >>= 1) acc += __shfl_down(acc, off, 64);
    __shared__ float red[4];
    int lane = threadIdx.x & 63, wv = threadIdx.x >> 6;
    if (lane == 0) red[wv] = acc;
    __syncthreads();
    if (threadIdx.x == 0) atomicAdd(out, red[0] + red[1] + red[2] + red[3]);
}

extern "C" void kernel_launch(void* const* d_in, const int* in_sizes, int n_in,
                              void* d_out, int out_size, void* d_ws, size_t ws_size,
                              hipStream_t stream) {
    const float* ds   = (const float*)d_in[0];   // [B, N, 2]
    const float* smap = (const float*)d_in[1];   // [B, 1, H, W] == [B, N]
    const float* u    = (const float*)d_in[2];   // [B, N, 2]
    const int*   kptr = (const int*)d_in[3];     // scalar K

    // workspace layout
    int*   hist = (int*)d_ws;                    // BATCH*NB
    int*   cnt  = hist + BATCH * NB;             // BATCH (contiguous with hist for one memset)
    int*   tbR  = cnt + BATCH;                   // 2*BATCH
    float* T    = (float*)(tbR + 2 * BATCH);     // BATCH
    int*   ncut = (int*)(T + BATCH);             // BATCH
    float* cval = (float*)(ncut + BATCH);        // BATCH*CAP
    int*   cidx = (int*)(cval + BATCH * CAP);    // BATCH*CAP

    hipMemsetAsync(hist, 0, (size_t)(BATCH * NB + BATCH) * sizeof(int), stream);
    hipMemsetAsync(d_out, 0, sizeof(float), stream);

    const int CBPB = 8;  // blocks per batch for hist/collect
    hist_kernel<<<BATCH * CBPB, 256, 0, stream>>>(smap, hist, CBPB);
    select_kernel<<<BATCH, 256, 0, stream>>>(hist, kptr, tbR);
    collect_kernel<<<BATCH * CBPB, 256, 0, stream>>>(smap, tbR, cnt, cval, cidx, CBPB);
    refine_kernel<<<BATCH, 256, 0, stream>>>(tbR, cnt, cval, cidx, T, ncut);
    loss_kernel<<<(BATCH * (NTOK / 2)) / 256, 256, 0, stream>>>(ds, u, smap, T, ncut,
                                                                (float*)d_out);
}

// Round 2
// 210.348 us; speedup vs baseline: 1.8497x; 1.8497x over previous
//
#include <hip/hip_runtime.h>

#define NB    4096      // histogram buckets over [0,1)
#define CAP   4096      // per-batch collect capacity (expected ~64 in threshold bucket)
#define BATCH 32
#define NTOK  262144    // 512*512
#define LOSS_BLOCKS 8192   // B*NTOK/4 tokens-per-thread / 256 threads

__device__ __forceinline__ int bucket_of(float v) {
    int b = (int)(v * (float)NB);
    return b > NB - 1 ? NB - 1 : b;
}

// --- Pass 1: per-batch histogram of s_map values ---
// 256 blocks x 1024 threads: 8 blocks per batch, 16 waves/block for latency hiding.
__global__ void hist_kernel(const float* __restrict__ smap, int* __restrict__ hist) {
    __shared__ int lh[NB];
    for (int i = threadIdx.x; i < NB; i += blockDim.x) lh[i] = 0;
    __syncthreads();
    const int cbpb = 8;
    int b  = blockIdx.x / cbpb;
    int cb = blockIdx.x % cbpb;
    const int chunk = NTOK / cbpb;                 // 32768 floats
    const float4* src = (const float4*)(smap + (size_t)b * NTOK + (size_t)cb * chunk);
    const int nf4 = chunk / 4;                     // 8192
    for (int i = threadIdx.x; i < nf4; i += blockDim.x) {
        float4 v = src[i];
        atomicAdd(&lh[bucket_of(v.x)], 1);
        atomicAdd(&lh[bucket_of(v.y)], 1);
        atomicAdd(&lh[bucket_of(v.z)], 1);
        atomicAdd(&lh[bucket_of(v.w)], 1);
    }
    __syncthreads();
    int* gh = hist + b * NB;
    for (int i = threadIdx.x; i < NB; i += blockDim.x) {
        int c = lh[i];
        if (c) atomicAdd(&gh[i], c);
    }
}

// --- Pass 2: find threshold bucket tb and residual rank R (1..hist[tb]) ---
__global__ void select_kernel(const int* __restrict__ hist, const int* __restrict__ kptr,
                              int* __restrict__ tbR) {
    int b = blockIdx.x;
    const int* gh = hist + b * NB;
    __shared__ int h[NB];
    __shared__ int csum[256];
    __shared__ int above[256];
    int t = threadIdx.x;
    const int C = NB / 256;  // 16 buckets per thread
    int base = t * C;
    int s = 0;
    for (int i = 0; i < C; i++) { int v = gh[base + i]; h[base + i] = v; s += v; }
    csum[t] = s;
    __syncthreads();
    if (t == 0) {
        int acc = 0;
        for (int c = 255; c >= 0; c--) { above[c] = acc; acc += csum[c]; }
    }
    __syncthreads();
    int K = *kptr;
    int cum = above[t];  // elements in buckets strictly above this chunk
    for (int i = C - 1; i >= 0; i--) {
        int hb = h[base + i];
        if (cum < K && cum + hb >= K) {
            tbR[2 * b]     = base + i;   // threshold bucket
            tbR[2 * b + 1] = K - cum;    // need R elements from it
        }
        cum += hb;
    }
}

// --- Pass 3: collect (value, index) of all elements in the threshold bucket ---
// 2048 blocks x 256 threads.
__global__ void collect_kernel(const float* __restrict__ smap, const int* __restrict__ tbR,
                               int* __restrict__ cnt, float* __restrict__ cval,
                               int* __restrict__ cidx) {
    const int cbpb = 64;
    int b  = blockIdx.x / cbpb;
    int cb = blockIdx.x % cbpb;
    const int chunk = NTOK / cbpb;                 // 4096 floats
    int tb = tbR[2 * b];
    const float4* src = (const float4*)(smap + (size_t)b * NTOK + (size_t)cb * chunk);
    const int nf4 = chunk / 4;                     // 1024
    int base_n = cb * chunk;
    for (int i = threadIdx.x; i < nf4; i += blockDim.x) {
        float4 v = src[i];
        float vals[4] = {v.x, v.y, v.z, v.w};
#pragma unroll
        for (int s = 0; s < 4; s++) {
            if (bucket_of(vals[s]) == tb) {
                int p = atomicAdd(&cnt[b], 1);
                if (p < CAP) {
                    cval[b * CAP + p] = vals[s];
                    cidx[b * CAP + p] = base_n + 4 * i + s;
                }
            }
        }
    }
}

// --- Pass 4: exact rank-(R-1) element under (value desc, index asc) ---
__global__ void refine_kernel(const int* __restrict__ tbR, const int* __restrict__ cnt,
                              const float* __restrict__ cval, const int* __restrict__ cidx,
                              float* __restrict__ T, int* __restrict__ ncut) {
    int b = blockIdx.x;
    int R = tbR[2 * b + 1];
    int M = cnt[b];
    bool overflow = (M > CAP);
    if (M > CAP) M = CAP;
    __shared__ float sv[CAP];
    __shared__ int   si[CAP];
    for (int i = threadIdx.x; i < M; i += blockDim.x) {
        sv[i] = cval[b * CAP + i];
        si[i] = cidx[b * CAP + i];
    }
    __syncthreads();
    if (overflow || R > M || R < 1) {
        if (threadIdx.x == 0) { T[b] = (float)tbR[2 * b] / (float)NB; ncut[b] = 0x7fffffff; }
        return;
    }
    for (int i = threadIdx.x; i < M; i += blockDim.x) {
        float vi = sv[i]; int ii = si[i];
        int r = 0;
        for (int j = 0; j < M; j++) {
            float vj = sv[j];
            r += (vj > vi) || (vj == vi && si[j] < ii);
        }
        if (r == R - 1) { T[b] = vi; ncut[b] = ii; }  // unique rank -> single writer
    }
}

__device__ __forceinline__ float token_loss(float d0, float d1, float u0, float u1,
                                            bool sel) {
    float g0 = -__logf(-__logf(u0));
    float g1 = -__logf(-__logf(u1));
    float dd = (d0 + g0) - (d1 + g1);
    float l  = __logf(1.f + __expf(-fabsf(dd)));
    float lp0 = (dd >= 0.f) ? -l      : dd - l;
    float lp1 = (dd >= 0.f) ? -l - dd : -l;
    lp0 = fmaxf(lp0, -100.f); lp1 = fmaxf(lp1, -100.f);
    return sel ? -lp0 : -lp1;
}

// --- Pass 5: fused gumbel-softmax BCE loss with threshold selection ---
// 4 tokens per thread; per-block partial sums (NO contended global atomics).
__global__ void loss_kernel(const float* __restrict__ ds, const float* __restrict__ u,
                            const float* __restrict__ smap, const float* __restrict__ T,
                            const int* __restrict__ ncut, float* __restrict__ partials) {
    int tid = blockIdx.x * blockDim.x + threadIdx.x;  // one thread = 4 tokens
    int b = tid >> 16;               // NTOK/4 = 65536 = 2^16 threads per batch
    int p = tid & 65535;             // float4-group index within batch
    const float4* ds4 = (const float4*)(ds + (size_t)b * NTOK * 2);
    const float4* u4  = (const float4*)(u  + (size_t)b * NTOK * 2);
    const float4* s4  = (const float4*)(smap + (size_t)b * NTOK);
    float4 dA = ds4[2 * p];
    float4 dB = ds4[2 * p + 1];
    float4 uA = u4[2 * p];
    float4 uB = u4[2 * p + 1];
    float4 sv = s4[p];
    float Tb = T[b];
    int   nc = ncut[b];
    int   n0 = p << 2;               // first token index of this thread

    bool s0 = (sv.x > Tb) || (sv.x == Tb && (n0 + 0) <= nc);
    bool s1 = (sv.y > Tb) || (sv.y == Tb && (n0 + 1) <= nc);
    bool s2 = (sv.z > Tb) || (sv.z == Tb && (n0 + 2) <= nc);
    bool s3 = (sv.w > Tb) || (sv.w == Tb && (n0 + 3) <= nc);

    float acc = token_loss(dA.x, dA.y, uA.x, uA.y, s0)
              + token_loss(dA.z, dA.w, uA.z, uA.w, s1)
              + token_loss(dB.x, dB.y, uB.x, uB.y, s2)
              + token_loss(dB.z, dB.w, uB.z, uB.w, s3);

    // wave(64) reduce, then cross-wave via LDS, one partial write per block
    for (int off = 32; off > 0; off >>= 1) acc += __shfl_down(acc, off, 64);
    __shared__ float red[4];
    int lane = threadIdx.x & 63, wv = threadIdx.x >> 6;
    if (lane == 0) red[wv] = acc;
    __syncthreads();
    if (threadIdx.x == 0)
        partials[blockIdx.x] = red[0] + red[1] + red[2] + red[3];
}

// --- Pass 6: reduce LOSS_BLOCKS partials into out[0] (single block) ---
__global__ void reduce_kernel(const float* __restrict__ partials, float* __restrict__ out) {
    float acc = 0.f;
    for (int i = threadIdx.x; i < LOSS_BLOCKS; i += blockDim.x) acc += partials[i];
    for (int off = 32; off > 0; off >>= 1) acc += __shfl_down(acc, off, 64);
    __shared__ float red[16];
    int lane = threadIdx.x & 63, wv = threadIdx.x >> 6;
    if (lane == 0) red[wv] = acc;
    __syncthreads();
    if (threadIdx.x == 0) {
        float s = 0.f;
        for (int w = 0; w < (int)(blockDim.x >> 6); w++) s += red[w];
        out[0] = s;
    }
}

extern "C" void kernel_launch(void* const* d_in, const int* in_sizes, int n_in,
                              void* d_out, int out_size, void* d_ws, size_t ws_size,
                              hipStream_t stream) {
    const float* ds   = (const float*)d_in[0];   // [B, N, 2]
    const float* smap = (const float*)d_in[1];   // [B, 1, H, W] == [B, N]
    const float* u    = (const float*)d_in[2];   // [B, N, 2]
    const int*   kptr = (const int*)d_in[3];     // scalar K

    // workspace layout
    int*   hist = (int*)d_ws;                    // BATCH*NB
    int*   cnt  = hist + BATCH * NB;             // BATCH (contiguous with hist: one memset)
    int*   tbR  = cnt + BATCH;                   // 2*BATCH
    float* T    = (float*)(tbR + 2 * BATCH);     // BATCH
    int*   ncut = (int*)(T + BATCH);             // BATCH
    float* cval = (float*)(ncut + BATCH);        // BATCH*CAP
    int*   cidx = (int*)(cval + BATCH * CAP);    // BATCH*CAP
    float* partials = (float*)(cidx + BATCH * CAP);  // LOSS_BLOCKS

    hipMemsetAsync(hist, 0, (size_t)(BATCH * NB + BATCH) * sizeof(int), stream);

    hist_kernel<<<256, 1024, 0, stream>>>(smap, hist);
    select_kernel<<<BATCH, 256, 0, stream>>>(hist, kptr, tbR);
    collect_kernel<<<2048, 256, 0, stream>>>(smap, tbR, cnt, cval, cidx);
    refine_kernel<<<BATCH, 256, 0, stream>>>(tbR, cnt, cval, cidx, T, ncut);
    loss_kernel<<<LOSS_BLOCKS, 256, 0, stream>>>(ds, u, smap, T, ncut, partials);
    reduce_kernel<<<1, 1024, 0, stream>>>(partials, (float*)d_out);
}